// Round 7
// baseline (216.324 us; speedup 1.0000x reference)
//
#include <hip/hip_runtime.h>
#include <hip/hip_bf16.h>

typedef __attribute__((ext_vector_type(8))) short bf16x8;
typedef __attribute__((ext_vector_type(4))) float f32x4;
typedef __attribute__((ext_vector_type(4))) short short4v;
typedef unsigned short ushort_t;

#define CC 120
#define LL 469
#define HH 64

constexpr int NBATCH = 1024;           // (s,b) pairs; raw reshape => batch contiguous
constexpr int KSTEPS = (LL + 31) / 32; // 15

// ---- LDS layout ----
// phase 1: Xl[2][120][40] bf16 @0 (19200 B), Wl[2][8192 shorts] @19200 (32768 B) -> 51968 B
//          W buffer = 16 KB: 15 live 1KB chunks ([192][40] bf16) + 1 pad chunk (uniform gload count)
// phase 2: Qb @0 (16 KB, [128]x128B swz), Kb @16384, Vb @32768 ([64]x256B swz)
//          Pb @0 (32 KB) aliases Q+K after QK^T barrier; epilogue Ob f32 [120][68] @0
constexpr int XB_STRIDE   = 40;                    // shorts
constexpr int XBUF_SHORTS = CC * XB_STRIDE;        // 4800
constexpr int WB_SHORTS   = 8192;                  // 16384 B per W buffer
constexpr int X_BYTES     = 2 * XBUF_SHORTS * 2;   // 19200
constexpr int SMEM_BYTES  = X_BYTES + 2 * WB_SHORTS * 2; // 51968
constexpr int WIMG_SHORTS = KSTEPS * WB_SHORTS;    // 122880
constexpr int WIMG_BYTES  = WIMG_SHORTS * 2;       // 245760

__device__ __forceinline__ ushort_t f2bf(float f) {
  __hip_bfloat16 h = __float2bfloat16(f);
  return __builtin_bit_cast(ushort_t, h);
}

__device__ __forceinline__ void gload_lds16(const void* g, void* l) {
  __builtin_amdgcn_global_load_lds(
      (const __attribute__((address_space(1))) unsigned int*)g,
      (__attribute__((address_space(3))) unsigned int*)l, 16, 0, 0);
}

// XOR-swizzled LDS address for phase-2 tiles
__device__ __forceinline__ char* sptr(char* base, int row, int stride, int byteoff) {
  return base + row * stride + (byteoff ^ ((row & 7) << 4));
}

// W image: per step t a 16 KB block; first 15360 B = [192 cols][40 k] bf16, rest pad.
__global__ void prep_w(const float* __restrict__ Wk, const float* __restrict__ Wq,
                       const float* __restrict__ Wv, ushort_t* __restrict__ wimg) {
  int idx = blockIdx.x * 256 + threadIdx.x; // 122880 exactly (480 blocks)
  int t = idx / WB_SHORTS;
  int r = idx % WB_SHORTS;
  int col = r / 40, kk = r % 40;
  float v = 0.f;
  if (r < 192 * 40 && kk < 32) {
    int k = t * 32 + kk;
    int wsel = col >> 6, h = col & 63;
    const float* wp = (wsel == 0) ? Wk : (wsel == 1) ? Wq : Wv;
    if (k < LL) v = wp[(size_t)k * HH + h];
  }
  wimg[idx] = f2bf(v);
}

template <bool WIMG>
__global__ __launch_bounds__(256, 3)
void fused_regional_head(const float* __restrict__ x,
                         const float* __restrict__ Wk,
                         const float* __restrict__ Wq,
                         const float* __restrict__ Wv,
                         const ushort_t* __restrict__ wimg,
                         float* __restrict__ out) {
  __shared__ char smem[SMEM_BYTES];
  const int tid = threadIdx.x;
  const int lane = tid & 63;
  const int wv = tid >> 6;   // wave 0..3, owns rows 32*wv .. 32*wv+31
  const int lr = lane & 15;
  const int lg = lane >> 4;
  const int batch = blockIdx.x;
  const size_t xbase = (size_t)batch * CC * LL;

  ushort_t* Xl = (ushort_t*)smem;                 // [2][120][40] bf16
  ushort_t* Wl = (ushort_t*)(smem + X_BYTES);     // [2][8192] shorts

  // staging decomposition: thread covers k-col (tid&31) of rows (tid>>5)+8i
  const int skk = tid & 31;
  const int sr0 = tid >> 5;

  // EXACTLY 15 loads per thread, unconditional (clamped address) -> deterministic vmcnt
  auto xload = [&](int t, float* v) {
    int k = t * 32 + skk;
    int kc = (k < LL) ? k : (LL - 1);
#pragma unroll
    for (int i = 0; i < 15; ++i)
      v[i] = x[xbase + (size_t)(i * 8 + sr0) * LL + kc];
  };
  auto xwrite = [&](int buf, const float* v, int t) {
    const bool ok = (t * 32 + skk) < LL;
    ushort_t* xb = Xl + buf * XBUF_SHORTS;
#pragma unroll
    for (int i = 0; i < 15; ++i)
      xb[(i * 8 + sr0) * XB_STRIDE + skk] = f2bf(ok ? v[i] : 0.f);
  };
  // EXACTLY 4 global_load_lds per thread (16 chunks of 1 KB, incl. pad chunk)
  auto stage_w_fast = [&](int buf, int t) {
    const char* src = (const char*)(wimg + (size_t)t * WB_SHORTS);
    char* dst = (char*)(Wl + buf * WB_SHORTS);
#pragma unroll
    for (int i = 0; i < 4; ++i) {
      int c = wv + 4 * i; // 0..15, uniform
      gload_lds16(src + c * 1024 + lane * 16, dst + c * 1024);
    }
  };
  auto stage_w_slow = [&](int buf, int t) {
    ushort_t* wb = Wl + buf * WB_SHORTS;
    const int k0 = t * 32;
#pragma unroll
    for (int j = 0; j < 24; ++j) {
      int idx = j * 256 + tid;
      int col = idx >> 5, kk = idx & 31;
      int k = k0 + kk;
      int wsel = col >> 6, h = col & 63;
      const float* wp = (wsel == 0) ? Wk : (wsel == 1) ? Wq : Wv;
      float v = (k < LL) ? wp[(size_t)k * HH + h] : 0.f;
      wb[col * 40 + kk] = f2bf(v);
    }
  };

  // ---------------- phase 1: QKV = X @ [Wk|Wq|Wv] ----------------
  f32x4 acc[2][12];
#pragma unroll
  for (int m = 0; m < 2; ++m)
#pragma unroll
    for (int n = 0; n < 12; ++n) acc[m][n] = (f32x4){0.f, 0.f, 0.f, 0.f};

  const int row0 = wv * 32 + lr;      // < 120 always
  const int row1 = wv * 32 + 16 + lr; // >= 120 for wave3, lr>=8
  const bool r1ok = row1 < CC;

  auto compute = [&](int t) {
    const ushort_t* xb = Xl + (t & 1) * XBUF_SHORTS;
    const ushort_t* wb = Wl + (t & 1) * WB_SHORTS;
    bf16x8 a0 = *(const bf16x8*)(xb + row0 * XB_STRIDE + lg * 8);
    bf16x8 a1;
    if (r1ok) a1 = *(const bf16x8*)(xb + row1 * XB_STRIDE + lg * 8);
    else { bf16x8 z = {0,0,0,0,0,0,0,0}; a1 = z; }
#pragma unroll
    for (int n = 0; n < 12; ++n) {
      bf16x8 b = *(const bf16x8*)(wb + (n * 16 + lr) * 40 + lg * 8);
      acc[0][n] = __builtin_amdgcn_mfma_f32_16x16x32_bf16(a0, b, acc[0][n], 0, 0, 0);
      acc[1][n] = __builtin_amdgcn_mfma_f32_16x16x32_bf16(a1, b, acc[1][n], 0, 0, 0);
    }
  };

  if constexpr (WIMG) {
    float xA[15], xB[15];
    // prologue: W(0) first (oldest), then X(0), X(1)
    stage_w_fast(0, 0);
    __builtin_amdgcn_sched_barrier(0);
    xload(0, xA);
    xload(1, xB);
    xwrite(0, xA, 0); // compiler auto-waits X(0) (covers W(0): both in oldest 19)
    asm volatile("s_waitcnt vmcnt(15) lgkmcnt(0)" ::: "memory");
    __builtin_amdgcn_s_barrier();
    __builtin_amdgcn_sched_barrier(0);

#pragma unroll
    for (int t = 0; t < KSTEPS; ++t) {
      float* fill = (t & 1) ? xB : xA; // dest for X(t+2)
      float* cons = (t & 1) ? xA : xB; // holds X(t+1)
      if (t + 1 < KSTEPS) {
        stage_w_fast((t + 1) & 1, t + 1); // W first: oldest of this step's issues
        __builtin_amdgcn_sched_barrier(0);
      }
      if (t + 2 < KSTEPS) xload(t + 2, fill); // rides through the barrier
      compute(t);
      if (t + 1 < KSTEPS) xwrite((t + 1) & 1, cons, t + 1); // auto vmcnt for cons
      if (t + 1 < KSTEPS) {
        if (t == KSTEPS - 2) { // no X(t+2) issued: drain fully
          asm volatile("s_waitcnt vmcnt(0) lgkmcnt(0)" ::: "memory");
        } else {               // wait W(t+1) (oldest 4), leave 15 X(t+2) in flight
          asm volatile("s_waitcnt vmcnt(15) lgkmcnt(0)" ::: "memory");
        }
        __builtin_amdgcn_s_barrier();
        __builtin_amdgcn_sched_barrier(0);
      }
    }
  } else {
    // fallback (unused when ws is large): r4 structure, full barriers
    float vx[15];
    xload(0, vx);
    xwrite(0, vx, 0);
    stage_w_slow(0, 0);
    __syncthreads();
#pragma unroll
    for (int t = 0; t < KSTEPS; ++t) {
      if (t + 1 < KSTEPS) xload(t + 1, vx);
      compute(t);
      if (t + 1 < KSTEPS) { xwrite((t + 1) & 1, vx, t + 1); stage_w_slow((t + 1) & 1, t + 1); }
      __syncthreads();
    }
  }
  __syncthreads(); // staging region dead; phase-2 tiles take over

  // ---------------- write Q,K,V (bf16, swizzled) ----------------
  char* Qb = smem;
  char* Kb = smem + 16384;
  char* Vb = smem + 32768;
  char* Pb = smem;
#pragma unroll
  for (int mt = 0; mt < 2; ++mt) {
#pragma unroll
    for (int r = 0; r < 4; ++r) {
      int row = wv * 32 + mt * 16 + lg * 4 + r;
#pragma unroll
      for (int n = 0; n < 4; ++n) {
        *(ushort_t*)sptr(Kb, row, 128, (n * 16 + lr) * 2) = f2bf(acc[mt][n][r]);
        *(ushort_t*)sptr(Qb, row, 128, (n * 16 + lr) * 2) = f2bf(acc[mt][4 + n][r]);
      }
    }
    // V^T packed: 4 consecutive d-rows -> ds_write_b64
#pragma unroll
    for (int n = 0; n < 4; ++n) {
      short4v pk;
#pragma unroll
      for (int r = 0; r < 4; ++r) pk[r] = (short)f2bf(acc[mt][8 + n][r]);
      *(short4v*)sptr(Vb, n * 16 + lr, 256, (wv * 32 + mt * 16 + lg * 4) * 2) = pk;
    }
  }
  __syncthreads();

  // ---------------- QK^T ----------------
  f32x4 accw[2][8];
#pragma unroll
  for (int m = 0; m < 2; ++m)
#pragma unroll
    for (int n = 0; n < 8; ++n) accw[m][n] = (f32x4){0.f, 0.f, 0.f, 0.f};
#pragma unroll
  for (int ks = 0; ks < 2; ++ks) {
    bf16x8 a0 = *(const bf16x8*)sptr(Qb, wv * 32 + lr, 128, ks * 64 + lg * 16);
    bf16x8 a1 = *(const bf16x8*)sptr(Qb, wv * 32 + 16 + lr, 128, ks * 64 + lg * 16);
#pragma unroll
    for (int n = 0; n < 8; ++n) {
      bf16x8 b = *(const bf16x8*)sptr(Kb, n * 16 + lr, 128, ks * 64 + lg * 16);
      accw[0][n] = __builtin_amdgcn_mfma_f32_16x16x32_bf16(a0, b, accw[0][n], 0, 0, 0);
      accw[1][n] = __builtin_amdgcn_mfma_f32_16x16x32_bf16(a1, b, accw[1][n], 0, 0, 0);
    }
  }
  __syncthreads(); // all done reading Q/K before P overwrites

  // ---------------- softmax (wave-parallel over 16-lane col groups) ----------------
#pragma unroll
  for (int mt = 0; mt < 2; ++mt)
#pragma unroll
    for (int r = 0; r < 4; ++r) {
      float l[8];
      float m = -1e30f;
#pragma unroll
      for (int n = 0; n < 8; ++n) {
        float v = accw[mt][n][r] * 0.125f;
        if (n == 7 && lr >= 8) v = -1e30f; // col = 112+lr >= 120 masked
        l[n] = v;
        m = fmaxf(m, v);
      }
#pragma unroll
      for (int off = 1; off < 16; off <<= 1) m = fmaxf(m, __shfl_xor(m, off));
      float s = 0.f;
#pragma unroll
      for (int n = 0; n < 8; ++n) {
        float p = __expf(l[n] - m);
        l[n] = p;
        s += p;
      }
#pragma unroll
      for (int off = 1; off < 16; off <<= 1) s += __shfl_xor(s, off);
      float inv = 1.f / s;
      int row = wv * 32 + mt * 16 + lg * 4 + r;
#pragma unroll
      for (int n = 0; n < 8; ++n)
        *(ushort_t*)sptr(Pb, row, 256, (n * 16 + lr) * 2) = f2bf(l[n] * inv);
    }
  // no barrier: each wave reads only its own P rows; V covered by barrier above

  // ---------------- out = P @ V ----------------
  f32x4 acco[2][4];
#pragma unroll
  for (int m = 0; m < 2; ++m)
#pragma unroll
    for (int n = 0; n < 4; ++n) acco[m][n] = (f32x4){0.f, 0.f, 0.f, 0.f};
#pragma unroll
  for (int ks = 0; ks < 4; ++ks) {
    bf16x8 a0 = *(const bf16x8*)sptr(Pb, wv * 32 + lr, 256, ks * 64 + lg * 16);
    bf16x8 a1 = *(const bf16x8*)sptr(Pb, wv * 32 + 16 + lr, 256, ks * 64 + lg * 16);
#pragma unroll
    for (int n = 0; n < 4; ++n) {
      bf16x8 b = *(const bf16x8*)sptr(Vb, n * 16 + lr, 256, ks * 64 + lg * 16);
      acco[0][n] = __builtin_amdgcn_mfma_f32_16x16x32_bf16(a0, b, acco[0][n], 0, 0, 0);
      acco[1][n] = __builtin_amdgcn_mfma_f32_16x16x32_bf16(a1, b, acco[1][n], 0, 0, 0);
    }
  }

  // ---------------- epilogue: LDS transpose -> float4 coalesced stores ----------------
  __syncthreads(); // P/V dead
  float* Ob = (float*)smem; // [120][68] f32
#pragma unroll
  for (int mt = 0; mt < 2; ++mt)
#pragma unroll
    for (int r = 0; r < 4; ++r) {
      int row = wv * 32 + mt * 16 + lg * 4 + r;
      if (row < CC) {
#pragma unroll
        for (int n = 0; n < 4; ++n)
          Ob[row * 68 + n * 16 + lr] = acco[mt][n][r];
      }
    }
  __syncthreads();
  const size_t obase = (size_t)batch * CC * HH;
#pragma unroll
  for (int i = 0; i < 8; ++i) {
    int idx = i * 256 + tid; // float4 index, 1920 total
    if (idx < 1920) {
      int row = idx >> 4;
      int c4 = (idx & 15) * 4;
      f32x4 v = *(const f32x4*)(Ob + row * 68 + c4);
      *(f32x4*)(out + obase + (size_t)idx * 4) = v;
    }
  }
}

extern "C" void kernel_launch(void* const* d_in, const int* in_sizes, int n_in,
                              void* d_out, int out_size, void* d_ws, size_t ws_size,
                              hipStream_t stream) {
  (void)in_sizes; (void)n_in; (void)out_size;
  const float* x  = (const float*)d_in[0];
  const float* Wk = (const float*)d_in[1];
  const float* Wq = (const float*)d_in[2];
  const float* Wv = (const float*)d_in[3];
  float* out = (float*)d_out;
  if (ws_size >= (size_t)WIMG_BYTES && d_ws != nullptr) {
    ushort_t* wimg = (ushort_t*)d_ws;
    prep_w<<<480, 256, 0, stream>>>(Wk, Wq, Wv, wimg);
    fused_regional_head<true><<<NBATCH, 256, 0, stream>>>(x, Wk, Wq, Wv, wimg, out);
  } else {
    fused_regional_head<false><<<NBATCH, 256, 0, stream>>>(x, Wk, Wq, Wv, nullptr, out);
  }
}

// Round 8
// 83.278 us; speedup vs baseline: 2.5976x; 2.5976x over previous
//
#include <hip/hip_runtime.h>
#include <hip/hip_bf16.h>

typedef __attribute__((ext_vector_type(8))) short bf16x8;
typedef __attribute__((ext_vector_type(4))) float f32x4;
typedef float f32x4u __attribute__((ext_vector_type(4), aligned(4))); // x rows only 4B-aligned (LL odd)
typedef __attribute__((ext_vector_type(4))) short short4v;
typedef unsigned short ushort_t;

#define CC 120
#define LL 469
#define HH 64

constexpr int NBATCH = 1024;           // (s,b) pairs; raw reshape => batch contiguous
constexpr int KSTEPS = (LL + 31) / 32; // 15

// ---- LDS layout ----
// phase 1: Xl[2][128][40] bf16 @0 (20480 B; rows 120..127 zero), Wl[2][192][40] bf16 @20480 (30720 B)
//          -> 51200 B => 3 blocks/CU
// phase 2: Qb @0 (16 KB, [128]x128B swz), Kb @16384, Vb @32768 ([64]x256B swz)
//          Pb @0 (32 KB) aliases Q+K after QK^T barrier; epilogue Ob f32 [120][68] @0
constexpr int XB_STRIDE   = 40;                    // shorts (80 B row, 16B-aligned)
constexpr int XBUF_SHORTS = 128 * XB_STRIDE;       // 5120
constexpr int WBUF_SHORTS = 192 * 40;              // 7680
constexpr int WBUF_BYTES  = WBUF_SHORTS * 2;       // 15360
constexpr int X_BYTES     = 2 * XBUF_SHORTS * 2;   // 20480
constexpr int SMEM_BYTES  = X_BYTES + 2 * WBUF_BYTES; // 51200 (phase2 needs 48K)
constexpr int WIMG_BYTES  = KSTEPS * WBUF_BYTES;   // 230400

__device__ __forceinline__ ushort_t f2bf(float f) {
  __hip_bfloat16 h = __float2bfloat16(f);
  return __builtin_bit_cast(ushort_t, h);
}

__device__ __forceinline__ void gload_lds16(const void* g, void* l) {
  __builtin_amdgcn_global_load_lds(
      (const __attribute__((address_space(1))) unsigned int*)g,
      (__attribute__((address_space(3))) unsigned int*)l, 16, 0, 0);
}

// XOR-swizzled LDS address for phase-2 tiles
__device__ __forceinline__ char* sptr(char* base, int row, int stride, int byteoff) {
  return base + row * stride + (byteoff ^ ((row & 7) << 4));
}

// W image: per step t, [192 cols][40 k] bf16 (k-pad zeroed)
__global__ void prep_w(const float* __restrict__ Wk, const float* __restrict__ Wq,
                       const float* __restrict__ Wv, ushort_t* __restrict__ wimg) {
  int idx = blockIdx.x * 256 + threadIdx.x; // 15*192*40 = 115200 exactly (450 blocks)
  int t = idx / (192 * 40);
  int rem = idx % (192 * 40);
  int col = rem / 40;
  int kk = rem % 40;
  int k = t * 32 + kk;
  int wsel = col >> 6, h = col & 63;
  const float* wp = (wsel == 0) ? Wk : (wsel == 1) ? Wq : Wv;
  float v = (kk < 32 && k < LL) ? wp[(size_t)k * HH + h] : 0.f;
  wimg[idx] = f2bf(v);
}

template <bool WIMG>
__global__ __launch_bounds__(256, 3)
void fused_regional_head(const float* __restrict__ x,
                         const float* __restrict__ Wk,
                         const float* __restrict__ Wq,
                         const float* __restrict__ Wv,
                         const ushort_t* __restrict__ wimg,
                         float* __restrict__ out) {
  __shared__ char smem[SMEM_BYTES];
  const int tid = threadIdx.x;
  const int lane = tid & 63;
  const int wv = tid >> 6;   // wave 0..3, owns rows 32*wv .. 32*wv+31
  const int lr = lane & 15;
  const int lg = lane >> 4;
  const int batch = blockIdx.x;
  const size_t xbase = (size_t)batch * CC * LL;

  ushort_t* Xl = (ushort_t*)smem;                 // [2][128][40] bf16
  ushort_t* Wl = (ushort_t*)(smem + X_BYTES);     // [2][192][40] bf16

  // X staging tasks: 128 rows x 8 chunks(16B) = 1024 tasks = 4/thread.
  // task = i*256+tid: row = task>>3 (0..127), chunk = task&7 (k = chunk*4..+3)
  auto xload = [&](int t, f32x4u* v) {
    const f32x4u z = (f32x4u){0.f, 0.f, 0.f, 0.f};
    if (t == KSTEPS - 1) { // tail: k = 448..468, element guards
#pragma unroll
      for (int i = 0; i < 4; ++i) {
        int task = i * 256 + tid, row = task >> 3, ch = task & 7;
        v[i] = z;
        if (row < CC) {
#pragma unroll
          for (int j = 0; j < 4; ++j) {
            int k = 448 + ch * 4 + j;
            if (k < LL) v[i][j] = x[xbase + (size_t)row * LL + k];
          }
        }
      }
    } else {
      const int k0 = t * 32;
#pragma unroll
      for (int i = 0; i < 4; ++i) {
        int task = i * 256 + tid, row = task >> 3, ch = task & 7;
        v[i] = (row < CC) ? *(const f32x4u*)(x + xbase + (size_t)row * LL + k0 + ch * 4) : z;
      }
    }
  };
  auto xwrite = [&](int buf, const f32x4u* v) {
    ushort_t* xb = Xl + buf * XBUF_SHORTS;
#pragma unroll
    for (int i = 0; i < 4; ++i) {
      int task = i * 256 + tid, row = task >> 3, ch = task & 7;
      short4v pk;
#pragma unroll
      for (int j = 0; j < 4; ++j) pk[j] = (short)f2bf(v[i][j]);
      *(short4v*)(xb + row * XB_STRIDE + ch * 4) = pk; // ds_write_b64
    }
  };

  auto stage_w = [&](int buf, int t) {
    ushort_t* wb = Wl + buf * WBUF_SHORTS;
    if constexpr (WIMG) {
      const char* src = (const char*)(wimg + t * WBUF_SHORTS);
#pragma unroll
      for (int i = 0; i < 4; ++i) {
        int c = wv + 4 * i; // 1024-byte chunks, 15 total
        if (c < 15) gload_lds16(src + c * 1024 + lane * 16, (char*)wb + c * 1024);
      }
    } else {
      const int k0 = t * 32;
#pragma unroll
      for (int j = 0; j < 24; ++j) {
        int idx = j * 256 + tid;
        int col = idx >> 5, kk = idx & 31;
        int k = k0 + kk;
        int wsel = col >> 6, h = col & 63;
        const float* wp = (wsel == 0) ? Wk : (wsel == 1) ? Wq : Wv;
        float v = (k < LL) ? wp[(size_t)k * HH + h] : 0.f;
        wb[col * 40 + kk] = f2bf(v);
      }
    }
  };

  // ---------------- phase 1: QKV = X @ [Wk|Wq|Wv] ----------------
  f32x4 acc[2][12];
#pragma unroll
  for (int m = 0; m < 2; ++m)
#pragma unroll
    for (int n = 0; n < 12; ++n) acc[m][n] = (f32x4){0.f, 0.f, 0.f, 0.f};

  const int row0 = wv * 32 + lr;
  const int row1 = wv * 32 + 16 + lr; // pad rows hold zeros -> no guard

  f32x4u vx[4];
  xload(0, vx);
  xwrite(0, vx);
  stage_w(0, 0);
  __syncthreads();

  for (int t = 0; t < KSTEPS; ++t) {
    // issue next-step loads first (full step of MFMA/ds_read cover)
    if (t + 1 < KSTEPS) {
      xload(t + 1, vx);
      stage_w((t + 1) & 1, t + 1);
    }
    const ushort_t* xb = Xl + (t & 1) * XBUF_SHORTS;
    const ushort_t* wb = Wl + (t & 1) * WBUF_SHORTS;
    bf16x8 a0 = *(const bf16x8*)(xb + row0 * XB_STRIDE + lg * 8);
    bf16x8 a1 = *(const bf16x8*)(xb + row1 * XB_STRIDE + lg * 8);
#pragma unroll
    for (int n = 0; n < 12; ++n) {
      bf16x8 b = *(const bf16x8*)(wb + (n * 16 + lr) * 40 + lg * 8);
      acc[0][n] = __builtin_amdgcn_mfma_f32_16x16x32_bf16(a0, b, acc[0][n], 0, 0, 0);
      acc[1][n] = __builtin_amdgcn_mfma_f32_16x16x32_bf16(a1, b, acc[1][n], 0, 0, 0);
    }
    if (t + 1 < KSTEPS) xwrite((t + 1) & 1, vx); // auto-vmcnt for vx, other buffer
    __syncthreads();
  }

  // ---------------- write Q,K,V (bf16, swizzled) ----------------
  char* Qb = smem;
  char* Kb = smem + 16384;
  char* Vb = smem + 32768;
  char* Pb = smem;
#pragma unroll
  for (int mt = 0; mt < 2; ++mt) {
#pragma unroll
    for (int r = 0; r < 4; ++r) {
      int row = wv * 32 + mt * 16 + lg * 4 + r;
#pragma unroll
      for (int n = 0; n < 4; ++n) {
        *(ushort_t*)sptr(Kb, row, 128, (n * 16 + lr) * 2) = f2bf(acc[mt][n][r]);
        *(ushort_t*)sptr(Qb, row, 128, (n * 16 + lr) * 2) = f2bf(acc[mt][4 + n][r]);
      }
    }
    // V^T packed: 4 consecutive d-rows -> ds_write_b64
#pragma unroll
    for (int n = 0; n < 4; ++n) {
      short4v pk;
#pragma unroll
      for (int r = 0; r < 4; ++r) pk[r] = (short)f2bf(acc[mt][8 + n][r]);
      *(short4v*)sptr(Vb, n * 16 + lr, 256, (wv * 32 + mt * 16 + lg * 4) * 2) = pk;
    }
  }
  __syncthreads();

  // ---------------- QK^T ----------------
  f32x4 accw[2][8];
#pragma unroll
  for (int m = 0; m < 2; ++m)
#pragma unroll
    for (int n = 0; n < 8; ++n) accw[m][n] = (f32x4){0.f, 0.f, 0.f, 0.f};
#pragma unroll
  for (int ks = 0; ks < 2; ++ks) {
    bf16x8 a0 = *(const bf16x8*)sptr(Qb, wv * 32 + lr, 128, ks * 64 + lg * 16);
    bf16x8 a1 = *(const bf16x8*)sptr(Qb, wv * 32 + 16 + lr, 128, ks * 64 + lg * 16);
#pragma unroll
    for (int n = 0; n < 8; ++n) {
      bf16x8 b = *(const bf16x8*)sptr(Kb, n * 16 + lr, 128, ks * 64 + lg * 16);
      accw[0][n] = __builtin_amdgcn_mfma_f32_16x16x32_bf16(a0, b, accw[0][n], 0, 0, 0);
      accw[1][n] = __builtin_amdgcn_mfma_f32_16x16x32_bf16(a1, b, accw[1][n], 0, 0, 0);
    }
  }
  __syncthreads(); // all done reading Q/K before P overwrites

  // ---------------- softmax (wave-parallel over 16-lane col groups) ----------------
#pragma unroll
  for (int mt = 0; mt < 2; ++mt)
#pragma unroll
    for (int r = 0; r < 4; ++r) {
      float l[8];
      float m = -1e30f;
#pragma unroll
      for (int n = 0; n < 8; ++n) {
        float v = accw[mt][n][r] * 0.125f;
        if (n == 7 && lr >= 8) v = -1e30f; // col = 112+lr >= 120 masked
        l[n] = v;
        m = fmaxf(m, v);
      }
#pragma unroll
      for (int off = 1; off < 16; off <<= 1) m = fmaxf(m, __shfl_xor(m, off));
      float s = 0.f;
#pragma unroll
      for (int n = 0; n < 8; ++n) {
        float p = __expf(l[n] - m);
        l[n] = p;
        s += p;
      }
#pragma unroll
      for (int off = 1; off < 16; off <<= 1) s += __shfl_xor(s, off);
      float inv = 1.f / s;
      int row = wv * 32 + mt * 16 + lg * 4 + r;
#pragma unroll
      for (int n = 0; n < 8; ++n)
        *(ushort_t*)sptr(Pb, row, 256, (n * 16 + lr) * 2) = f2bf(l[n] * inv);
    }
  // no barrier: each wave reads only its own P rows; V covered by barrier above

  // ---------------- out = P @ V ----------------
  f32x4 acco[2][4];
#pragma unroll
  for (int m = 0; m < 2; ++m)
#pragma unroll
    for (int n = 0; n < 4; ++n) acco[m][n] = (f32x4){0.f, 0.f, 0.f, 0.f};
#pragma unroll
  for (int ks = 0; ks < 4; ++ks) {
    bf16x8 a0 = *(const bf16x8*)sptr(Pb, wv * 32 + lr, 256, ks * 64 + lg * 16);
    bf16x8 a1 = *(const bf16x8*)sptr(Pb, wv * 32 + 16 + lr, 256, ks * 64 + lg * 16);
#pragma unroll
    for (int n = 0; n < 4; ++n) {
      bf16x8 b = *(const bf16x8*)sptr(Vb, n * 16 + lr, 256, ks * 64 + lg * 16);
      acco[0][n] = __builtin_amdgcn_mfma_f32_16x16x32_bf16(a0, b, acco[0][n], 0, 0, 0);
      acco[1][n] = __builtin_amdgcn_mfma_f32_16x16x32_bf16(a1, b, acco[1][n], 0, 0, 0);
    }
  }

  // ---------------- epilogue: LDS transpose -> float4 coalesced stores ----------------
  __syncthreads(); // P/V dead
  float* Ob = (float*)smem; // [120][68] f32
#pragma unroll
  for (int mt = 0; mt < 2; ++mt)
#pragma unroll
    for (int r = 0; r < 4; ++r) {
      int row = wv * 32 + mt * 16 + lg * 4 + r;
      if (row < CC) {
#pragma unroll
        for (int n = 0; n < 4; ++n)
          Ob[row * 68 + n * 16 + lr] = acco[mt][n][r];
      }
    }
  __syncthreads();
  const size_t obase = (size_t)batch * CC * HH;
#pragma unroll
  for (int i = 0; i < 8; ++i) {
    int idx = i * 256 + tid; // float4 index, 1920 total
    if (idx < 1920) {
      int row = idx >> 4;
      int c4 = (idx & 15) * 4;
      f32x4 v = *(const f32x4*)(Ob + row * 68 + c4);
      *(f32x4*)(out + obase + (size_t)idx * 4) = v;
    }
  }
}

extern "C" void kernel_launch(void* const* d_in, const int* in_sizes, int n_in,
                              void* d_out, int out_size, void* d_ws, size_t ws_size,
                              hipStream_t stream) {
  (void)in_sizes; (void)n_in; (void)out_size;
  const float* x  = (const float*)d_in[0];
  const float* Wk = (const float*)d_in[1];
  const float* Wq = (const float*)d_in[2];
  const float* Wv = (const float*)d_in[3];
  float* out = (float*)d_out;
  if (ws_size >= (size_t)WIMG_BYTES && d_ws != nullptr) {
    ushort_t* wimg = (ushort_t*)d_ws;
    prep_w<<<450, 256, 0, stream>>>(Wk, Wq, Wv, wimg);
    fused_regional_head<true><<<NBATCH, 256, 0, stream>>>(x, Wk, Wq, Wv, wimg, out);
  } else {
    fused_regional_head<false><<<NBATCH, 256, 0, stream>>>(x, Wk, Wq, Wv, nullptr, out);
  }
}

// Round 9
// 68.497 us; speedup vs baseline: 3.1581x; 1.2158x over previous
//
#include <hip/hip_runtime.h>
#include <hip/hip_bf16.h>

typedef __attribute__((ext_vector_type(8))) short bf16x8;
typedef __attribute__((ext_vector_type(4))) float f32x4;
typedef __attribute__((ext_vector_type(4))) short short4v;
typedef unsigned short ushort_t;

#define CC 120
#define LL 469
#define HH 64

constexpr int NBATCH = 1024;           // (s,b) pairs; raw reshape => batch contiguous
constexpr int KSTEPS = (LL + 31) / 32; // 15

// ---- LDS layout ----
// phase 1: Xf[2][120][32] f32 @0 (30720 B, source-chunk-XOR swizzled),
//          Wl[2][8192 shorts] @30720 (32768 B; 15 live 1KB chunks + 1 pad chunk)
//          -> 63488 B => 2 blocks/CU. ALL staging via global_load_lds (no regs, no ds_write).
// phase 2: Qb @0 (16 KB, [128]x128B swz), Kb @16384, Vb @32768 ([64]x256B swz)
//          Pb @0 (32 KB) aliases Q+K after QK^T barrier; epilogue Ob f32 [120][68] @0
constexpr int XBUF_FLOATS = 120 * 32;              // 3840 dwords = 15/thread
constexpr int X_BYTES     = 2 * XBUF_FLOATS * 4;   // 30720
constexpr int WB_SHORTS   = 8192;                  // 16 KB per W buffer (padded)
constexpr int SMEM_BYTES  = X_BYTES + 2 * WB_SHORTS * 2; // 63488
constexpr int WIMG_SHORTS = KSTEPS * WB_SHORTS;    // 122880
constexpr int WIMG_BYTES  = WIMG_SHORTS * 2;       // 245760

__device__ __forceinline__ ushort_t f2bf(float f) {
  __hip_bfloat16 h = __float2bfloat16(f);
  return __builtin_bit_cast(ushort_t, h);
}

__device__ __forceinline__ void gload_lds4(const void* g, void* l) {
  __builtin_amdgcn_global_load_lds(
      (const __attribute__((address_space(1))) unsigned int*)g,
      (__attribute__((address_space(3))) unsigned int*)l, 4, 0, 0);
}
__device__ __forceinline__ void gload_lds16(const void* g, void* l) {
  __builtin_amdgcn_global_load_lds(
      (const __attribute__((address_space(1))) unsigned int*)g,
      (__attribute__((address_space(3))) unsigned int*)l, 16, 0, 0);
}

// XOR-swizzled LDS address for phase-2 tiles
__device__ __forceinline__ char* sptr(char* base, int row, int stride, int byteoff) {
  return base + row * stride + (byteoff ^ ((row & 7) << 4));
}

// W image: per step t a 16 KB block; first 15360 B = [192 cols][40 k] bf16, rest pad.
__global__ void prep_w(const float* __restrict__ Wk, const float* __restrict__ Wq,
                       const float* __restrict__ Wv, ushort_t* __restrict__ wimg) {
  int idx = blockIdx.x * 256 + threadIdx.x; // 122880 exactly (480 blocks)
  int t = idx / WB_SHORTS;
  int r = idx % WB_SHORTS;
  int col = r / 40, kk = r % 40;
  float v = 0.f;
  if (r < 192 * 40 && kk < 32) {
    int k = t * 32 + kk;
    int wsel = col >> 6, h = col & 63;
    const float* wp = (wsel == 0) ? Wk : (wsel == 1) ? Wq : Wv;
    if (k < LL) v = wp[(size_t)k * HH + h];
  }
  wimg[idx] = f2bf(v);
}

template <bool WIMG>
__global__ __launch_bounds__(256, 2)
void fused_regional_head(const float* __restrict__ x,
                         const float* __restrict__ Wk,
                         const float* __restrict__ Wq,
                         const float* __restrict__ Wv,
                         const ushort_t* __restrict__ wimg,
                         float* __restrict__ out) {
  __shared__ char smem[SMEM_BYTES];
  const int tid = threadIdx.x;
  const int lane = tid & 63;
  const int wv = tid >> 6;   // wave 0..3, owns rows 32*wv .. 32*wv+31
  const int lr = lane & 15;
  const int lg = lane >> 4;
  const int batch = blockIdx.x;
  const size_t xbase = (size_t)batch * CC * LL;

  float* Xf = (float*)smem;                       // [2][120][32] f32, chunk-swizzled
  ushort_t* Wl = (ushort_t*)(smem + X_BYTES);     // [2][8192] shorts

  // X stage: 15 gload_lds4 per thread, uniform count. LDS linear; global source
  // chunk-XOR-swizzled so ds_read of logical 16B chunk s reads phys s^(row&7).
  auto stage_x = [&](int t) {
    float* dst = Xf + (t & 1) * XBUF_FLOATS;
    const int k0 = t * 32;
    const bool tail = (t == KSTEPS - 1);
#pragma unroll
    for (int i = 0; i < 15; ++i) {
      int slot = i * 4 + wv;              // 0..59, wave-uniform
      int dw = slot * 64 + lane;          // dword in [0,3840)
      int row = dw >> 5;
      int w = dw & 31;
      int lw = (((w >> 2) ^ (row & 7)) << 2) | (w & 3); // logical k-word
      int k = k0 + lw;
      if (tail) {
        if (k >= LL) dst[dw] = 0.f;       // zero invalid lanes (lgkm, drained at barrier)
        if (k < LL) gload_lds4(x + xbase + (size_t)row * LL + k, dst + slot * 64);
      } else {
        gload_lds4(x + xbase + (size_t)row * LL + k, dst + slot * 64);
      }
    }
  };
  // W stage: exactly 4 gload_lds16 per thread (16 chunks of 1 KB incl. pad chunk)
  auto stage_w_fast = [&](int t) {
    const char* src = (const char*)(wimg + (size_t)t * WB_SHORTS);
    char* dst = (char*)(Wl + (t & 1) * WB_SHORTS);
#pragma unroll
    for (int i = 0; i < 4; ++i) {
      int c = wv + 4 * i; // 0..15, uniform
      gload_lds16(src + c * 1024 + lane * 16, dst + c * 1024);
    }
  };
  auto stage_w_slow = [&](int t) {
    ushort_t* wb = Wl + (t & 1) * WB_SHORTS;
    const int k0 = t * 32;
#pragma unroll
    for (int j = 0; j < 24; ++j) {
      int idx = j * 256 + tid;
      int col = idx >> 5, kk = idx & 31;
      int k = k0 + kk;
      int wsel = col >> 6, h = col & 63;
      const float* wp = (wsel == 0) ? Wk : (wsel == 1) ? Wq : Wv;
      float v = (k < LL) ? wp[(size_t)k * HH + h] : 0.f;
      wb[col * 40 + kk] = f2bf(v);
    }
  };

  // ---------------- phase 1: QKV = X @ [Wk|Wq|Wv] ----------------
  f32x4 acc[2][12];
#pragma unroll
  for (int m = 0; m < 2; ++m)
#pragma unroll
    for (int n = 0; n < 12; ++n) acc[m][n] = (f32x4){0.f, 0.f, 0.f, 0.f};

  const int row0 = wv * 32 + lr;      // < 120 always
  const int row1 = wv * 32 + 16 + lr; // >= 120 for wave3, lr>=8
  const bool r1ok = row1 < CC;

  auto compute = [&](int t) {
    const float* xb = Xf + (t & 1) * XBUF_FLOATS;
    const ushort_t* wb = Wl + (t & 1) * WB_SHORTS;
    f32x4 z = (f32x4){0.f, 0.f, 0.f, 0.f};
    f32x4 c00 = *(const f32x4*)(xb + row0 * 32 + (((lg * 2) ^ (row0 & 7)) << 2));
    f32x4 c01 = *(const f32x4*)(xb + row0 * 32 + (((lg * 2 + 1) ^ (row0 & 7)) << 2));
    f32x4 c10 = r1ok ? *(const f32x4*)(xb + row1 * 32 + (((lg * 2) ^ (row1 & 7)) << 2)) : z;
    f32x4 c11 = r1ok ? *(const f32x4*)(xb + row1 * 32 + (((lg * 2 + 1) ^ (row1 & 7)) << 2)) : z;
    bf16x8 a0, a1;
#pragma unroll
    for (int j = 0; j < 4; ++j) {
      a0[j] = (short)f2bf(c00[j]); a0[4 + j] = (short)f2bf(c01[j]);
      a1[j] = (short)f2bf(c10[j]); a1[4 + j] = (short)f2bf(c11[j]);
    }
#pragma unroll
    for (int n = 0; n < 12; ++n) {
      bf16x8 b = *(const bf16x8*)(wb + (n * 16 + lr) * 40 + lg * 8);
      acc[0][n] = __builtin_amdgcn_mfma_f32_16x16x32_bf16(a0, b, acc[0][n], 0, 0, 0);
      acc[1][n] = __builtin_amdgcn_mfma_f32_16x16x32_bf16(a1, b, acc[1][n], 0, 0, 0);
    }
  };

  if constexpr (WIMG) {
    // 2-deep pipeline: per step issue S(t+1) (19 VMEM/wave, uniform), then wait
    // vmcnt(19) => drains S(t) only; S(t+1) rides through the barrier.
    stage_x(0);
    stage_w_fast(0);
    for (int t = 0; t < KSTEPS; ++t) {
      if (t + 1 < KSTEPS) {
        stage_x(t + 1);
        stage_w_fast(t + 1);
        asm volatile("s_waitcnt vmcnt(19) lgkmcnt(0)" ::: "memory");
      } else {
        asm volatile("s_waitcnt vmcnt(0) lgkmcnt(0)" ::: "memory");
      }
      __builtin_amdgcn_s_barrier();
      __builtin_amdgcn_sched_barrier(0);
      compute(t);
    }
  } else {
    stage_x(0);
    stage_w_slow(0);
    __syncthreads();
    for (int t = 0; t < KSTEPS; ++t) {
      if (t + 1 < KSTEPS) { stage_x(t + 1); stage_w_slow(t + 1); }
      compute(t);
      __syncthreads();
    }
  }
  __syncthreads(); // staging region dead; phase-2 tiles take over

  // ---------------- write Q,K,V (bf16, swizzled) ----------------
  char* Qb = smem;
  char* Kb = smem + 16384;
  char* Vb = smem + 32768;
  char* Pb = smem;
#pragma unroll
  for (int mt = 0; mt < 2; ++mt) {
#pragma unroll
    for (int r = 0; r < 4; ++r) {
      int row = wv * 32 + mt * 16 + lg * 4 + r;
#pragma unroll
      for (int n = 0; n < 4; ++n) {
        *(ushort_t*)sptr(Kb, row, 128, (n * 16 + lr) * 2) = f2bf(acc[mt][n][r]);
        *(ushort_t*)sptr(Qb, row, 128, (n * 16 + lr) * 2) = f2bf(acc[mt][4 + n][r]);
      }
    }
    // V^T packed: 4 consecutive d-rows -> ds_write_b64
#pragma unroll
    for (int n = 0; n < 4; ++n) {
      short4v pk;
#pragma unroll
      for (int r = 0; r < 4; ++r) pk[r] = (short)f2bf(acc[mt][8 + n][r]);
      *(short4v*)sptr(Vb, n * 16 + lr, 256, (wv * 32 + mt * 16 + lg * 4) * 2) = pk;
    }
  }
  __syncthreads();

  // ---------------- QK^T ----------------
  f32x4 accw[2][8];
#pragma unroll
  for (int m = 0; m < 2; ++m)
#pragma unroll
    for (int n = 0; n < 8; ++n) accw[m][n] = (f32x4){0.f, 0.f, 0.f, 0.f};
#pragma unroll
  for (int ks = 0; ks < 2; ++ks) {
    bf16x8 a0 = *(const bf16x8*)sptr(Qb, wv * 32 + lr, 128, ks * 64 + lg * 16);
    bf16x8 a1 = *(const bf16x8*)sptr(Qb, wv * 32 + 16 + lr, 128, ks * 64 + lg * 16);
#pragma unroll
    for (int n = 0; n < 8; ++n) {
      bf16x8 b = *(const bf16x8*)sptr(Kb, n * 16 + lr, 128, ks * 64 + lg * 16);
      accw[0][n] = __builtin_amdgcn_mfma_f32_16x16x32_bf16(a0, b, accw[0][n], 0, 0, 0);
      accw[1][n] = __builtin_amdgcn_mfma_f32_16x16x32_bf16(a1, b, accw[1][n], 0, 0, 0);
    }
  }
  __syncthreads(); // all done reading Q/K before P overwrites

  // ---------------- softmax (wave-parallel over 16-lane col groups) ----------------
#pragma unroll
  for (int mt = 0; mt < 2; ++mt)
#pragma unroll
    for (int r = 0; r < 4; ++r) {
      float l[8];
      float m = -1e30f;
#pragma unroll
      for (int n = 0; n < 8; ++n) {
        float v = accw[mt][n][r] * 0.125f;
        if (n == 7 && lr >= 8) v = -1e30f; // col = 112+lr >= 120 masked
        l[n] = v;
        m = fmaxf(m, v);
      }
#pragma unroll
      for (int off = 1; off < 16; off <<= 1) m = fmaxf(m, __shfl_xor(m, off));
      float s = 0.f;
#pragma unroll
      for (int n = 0; n < 8; ++n) {
        float p = __expf(l[n] - m);
        l[n] = p;
        s += p;
      }
#pragma unroll
      for (int off = 1; off < 16; off <<= 1) s += __shfl_xor(s, off);
      float inv = 1.f / s;
      int row = wv * 32 + mt * 16 + lg * 4 + r;
#pragma unroll
      for (int n = 0; n < 8; ++n)
        *(ushort_t*)sptr(Pb, row, 256, (n * 16 + lr) * 2) = f2bf(l[n] * inv);
    }
  // no barrier: each wave reads only its own P rows; V covered by barrier above

  // ---------------- out = P @ V ----------------
  f32x4 acco[2][4];
#pragma unroll
  for (int m = 0; m < 2; ++m)
#pragma unroll
    for (int n = 0; n < 4; ++n) acco[m][n] = (f32x4){0.f, 0.f, 0.f, 0.f};
#pragma unroll
  for (int ks = 0; ks < 4; ++ks) {
    bf16x8 a0 = *(const bf16x8*)sptr(Pb, wv * 32 + lr, 256, ks * 64 + lg * 16);
    bf16x8 a1 = *(const bf16x8*)sptr(Pb, wv * 32 + 16 + lr, 256, ks * 64 + lg * 16);
#pragma unroll
    for (int n = 0; n < 4; ++n) {
      bf16x8 b = *(const bf16x8*)sptr(Vb, n * 16 + lr, 256, ks * 64 + lg * 16);
      acco[0][n] = __builtin_amdgcn_mfma_f32_16x16x32_bf16(a0, b, acco[0][n], 0, 0, 0);
      acco[1][n] = __builtin_amdgcn_mfma_f32_16x16x32_bf16(a1, b, acco[1][n], 0, 0, 0);
    }
  }

  // ---------------- epilogue: LDS transpose -> float4 coalesced stores ----------------
  __syncthreads(); // P/V dead
  float* Ob = (float*)smem; // [120][68] f32
#pragma unroll
  for (int mt = 0; mt < 2; ++mt)
#pragma unroll
    for (int r = 0; r < 4; ++r) {
      int row = wv * 32 + mt * 16 + lg * 4 + r;
      if (row < CC) {
#pragma unroll
        for (int n = 0; n < 4; ++n)
          Ob[row * 68 + n * 16 + lr] = acco[mt][n][r];
      }
    }
  __syncthreads();
  const size_t obase = (size_t)batch * CC * HH;
#pragma unroll
  for (int i = 0; i < 8; ++i) {
    int idx = i * 256 + tid; // float4 index, 1920 total
    if (idx < 1920) {
      int row = idx >> 4;
      int c4 = (idx & 15) * 4;
      f32x4 v = *(const f32x4*)(Ob + row * 68 + c4);
      *(f32x4*)(out + obase + (size_t)idx * 4) = v;
    }
  }
}

extern "C" void kernel_launch(void* const* d_in, const int* in_sizes, int n_in,
                              void* d_out, int out_size, void* d_ws, size_t ws_size,
                              hipStream_t stream) {
  (void)in_sizes; (void)n_in; (void)out_size;
  const float* x  = (const float*)d_in[0];
  const float* Wk = (const float*)d_in[1];
  const float* Wq = (const float*)d_in[2];
  const float* Wv = (const float*)d_in[3];
  float* out = (float*)d_out;
  if (ws_size >= (size_t)WIMG_BYTES && d_ws != nullptr) {
    ushort_t* wimg = (ushort_t*)d_ws;
    prep_w<<<480, 256, 0, stream>>>(Wk, Wq, Wv, wimg);
    fused_regional_head<true><<<NBATCH, 256, 0, stream>>>(x, Wk, Wq, Wv, wimg, out);
  } else {
    fused_regional_head<false><<<NBATCH, 256, 0, stream>>>(x, Wk, Wq, Wv, nullptr, out);
  }
}